// Round 1
// baseline (2304.027 us; speedup 1.0000x reference)
//
#include <hip/hip_runtime.h>
#include <hip/hip_bf16.h>
#include <cfloat>
#include <cmath>

// Problem constants
#define H_DIM 768
#define IDX_D 64
#define KTOP 10
#define R_HEADS 12
#define READ_K 100
#define MD 64
#define WK 100
#define INTER 3072
#define N_NODES 50000
#define B_SZ 4
#define E_SZ 128
#define BE 512            // B*E
#define SLOTS 110         // KTOP + READ_K
#define HASH_SZ 2048
#define HASH_MASK 2047

// ---------------------------------------------------------------------------
// small utility kernels
// ---------------------------------------------------------------------------
__global__ void zero_loss_kernel(float* p) {
    if (threadIdx.x == 0 && blockIdx.x == 0) *p = 0.f;
}
__global__ void write_loss_kernel(const float* p, float* out) {
    if (threadIdx.x == 0 && blockIdx.x == 0) out[0] = *p / 65536.f;  // / (B*E*E)
}

// ---------------------------------------------------------------------------
// generic f32 GEMM:  C[M,N] = A[M,K] @ B[K,N] + bias[N], optional exact GELU
// 64x64 tile, 256 threads, 4x4 micro-tile, K-tile 16. All dims divide evenly.
// ---------------------------------------------------------------------------
__global__ __launch_bounds__(256) void gemm_kernel(
    const float* __restrict__ A, const float* __restrict__ Bm,
    const float* __restrict__ bias, float* __restrict__ C,
    int M, int N, int K, int act)
{
    __shared__ float As[16][65];
    __shared__ float Bs[16][65];
    const int tid = threadIdx.x;
    const int tx = tid & 15, ty = tid >> 4;
    const int m0 = blockIdx.y * 64, n0 = blockIdx.x * 64;

    float acc[4][4] = {};
    for (int k0 = 0; k0 < K; k0 += 16) {
        for (int l = tid; l < 1024; l += 256) {
            int mm = l >> 4, kk = l & 15;
            As[kk][mm] = A[(size_t)(m0 + mm) * K + k0 + kk];
        }
        for (int l = tid; l < 1024; l += 256) {
            int kk = l >> 6, nn = l & 63;
            Bs[kk][nn] = Bm[(size_t)(k0 + kk) * N + n0 + nn];
        }
        __syncthreads();
        #pragma unroll
        for (int kk = 0; kk < 16; ++kk) {
            float av[4], bv[4];
            #pragma unroll
            for (int u = 0; u < 4; ++u) av[u] = As[kk][ty * 4 + u];
            #pragma unroll
            for (int v = 0; v < 4; ++v) bv[v] = Bs[kk][tx * 4 + v];
            #pragma unroll
            for (int u = 0; u < 4; ++u)
                #pragma unroll
                for (int v = 0; v < 4; ++v) acc[u][v] += av[u] * bv[v];
        }
        __syncthreads();
    }
    #pragma unroll
    for (int u = 0; u < 4; ++u) {
        int m = m0 + ty * 4 + u;
        #pragma unroll
        for (int v = 0; v < 4; ++v) {
            int n = n0 + tx * 4 + v;
            float x = acc[u][v] + bias[n];
            if (act) x = 0.5f * x * (1.f + erff(x * 0.70710678118654752f)); // exact gelu
            C[(size_t)m * N + n] = x;
        }
    }
}

// ---------------------------------------------------------------------------
// indexer: hierarchical product-key top-k.  1 block (64 threads = 1 wave) per
// (b,e) row.  Sets at each level are order-invariant downstream, so iterative
// argmax extraction is sufficient.
// ---------------------------------------------------------------------------
__device__ inline void wave_topk10(volatile float* a, int cnt,
                                   float* vnew, int* inew, int t)
{
    for (int iter = 0; iter < 10; ++iter) {
        float bv = -FLT_MAX;
        int bi = 0x7fffffff;
        for (int n = t; n < cnt; n += 64) {
            float v = a[n];
            if (v > bv) { bv = v; bi = n; }
        }
        #pragma unroll
        for (int off = 32; off; off >>= 1) {
            float ov = __shfl_xor(bv, off, 64);
            int   oi = __shfl_xor(bi, off, 64);
            if (ov > bv || (ov == bv && oi < bi)) { bv = ov; bi = oi; }
        }
        if (t == 0) { vnew[iter] = bv; inew[iter] = bi; a[bi] = -FLT_MAX; }
        __syncthreads();
    }
}

__global__ __launch_bounds__(64) void indexer_kernel(
    const float* __restrict__ qidx,   // [BE][256]
    const float* __restrict__ key0,   // [100][64]
    const float* __restrict__ key1,   // [100][10][64]
    const float* __restrict__ key2,   // [1000][10][64]
    const float* __restrict__ key3,   // [10000][5][64]
    float* __restrict__ e2n_val,      // [BE][10]
    int* __restrict__ e2n_ind)        // [BE][10]
{
    const int be = blockIdx.x;
    const int t = threadIdx.x;
    __shared__ float q[256];
    __shared__ float sraw[100];
    __shared__ float a[100];
    __shared__ float vnew[10]; __shared__ int inew[10];
    __shared__ float vcur[10]; __shared__ int icur[10];
    __shared__ float km[10], ks[10];

    for (int idx = t; idx < 256; idx += 64) q[idx] = qidx[(size_t)be * 256 + idx];
    __syncthreads();

    // ---- level 0: softmax over 100 nodes, top-10 ----
    for (int n = t; n < 100; n += 64) {
        float dot = 0.f;
        const float* kp = key0 + (size_t)n * 64;
        #pragma unroll 8
        for (int d = 0; d < 64; ++d) dot += q[d] * kp[d];
        sraw[n] = dot * 0.125f;   // / sqrt(64)
    }
    __syncthreads();
    float lm = -FLT_MAX;
    for (int n = t; n < 100; n += 64) lm = fmaxf(lm, sraw[n]);
    #pragma unroll
    for (int off = 32; off; off >>= 1) lm = fmaxf(lm, __shfl_xor(lm, off, 64));
    float lsum = 0.f;
    for (int n = t; n < 100; n += 64) { float e = expf(sraw[n] - lm); a[n] = e; lsum += e; }
    #pragma unroll
    for (int off = 32; off; off >>= 1) lsum += __shfl_xor(lsum, off, 64);
    __syncthreads();
    for (int n = t; n < 100; n += 64) a[n] /= lsum;
    __syncthreads();
    wave_topk10(a, 100, vnew, inew, t);
    if (t == 0) {
        float s = 0.f;
        for (int u = 0; u < 10; ++u) s += vnew[u];
        for (int u = 0; u < 10; ++u) { vcur[u] = vnew[u] / s; icur[u] = inew[u]; }
    }
    __syncthreads();

    // ---- levels 1..3 ----
    for (int lvl = 1; lvl < 4; ++lvl) {
        const int br = (lvl < 3) ? 10 : 5;
        const float* kb = (lvl == 1) ? key1 : ((lvl == 2) ? key2 : key3);
        const int cnt = 10 * br;
        const float* qv = q + lvl * 64;
        for (int c = t; c < cnt; c += 64) {
            int k = c / br, cc = c - k * br;
            const float* kp = kb + ((size_t)icur[k] * br + cc) * 64;
            float dot = 0.f;
            #pragma unroll 8
            for (int d = 0; d < 64; ++d) dot += qv[d] * kp[d];
            sraw[c] = dot * 0.125f;
        }
        __syncthreads();
        if (t < 10) {  // per-k softmax over branch
            float m = -FLT_MAX;
            for (int cc = 0; cc < br; ++cc) m = fmaxf(m, sraw[t * br + cc]);
            float s = 0.f;
            for (int cc = 0; cc < br; ++cc) s += expf(sraw[t * br + cc] - m);
            km[t] = m; ks[t] = s;
        }
        __syncthreads();
        for (int c = t; c < cnt; c += 64) {
            int k = c / br;
            a[c] = vcur[k] * expf(sraw[c] - km[k]) / ks[k];
        }
        __syncthreads();
        wave_topk10(a, cnt, vnew, inew, t);
        if (t == 0) {
            float s = 0.f;
            for (int u = 0; u < 10; ++u) s += vnew[u];
            int ni[10]; float nv[10];
            for (int u = 0; u < 10; ++u) {
                int f = inew[u];
                ni[u] = icur[f / br] * br + (f % br);
                nv[u] = vnew[u] / s;
            }
            for (int u = 0; u < 10; ++u) { icur[u] = ni[u]; vcur[u] = nv[u]; }
        }
        __syncthreads();
    }
    if (t < 10) {
        e2n_val[(size_t)be * 10 + t] = vcur[t];
        e2n_ind[(size_t)be * 10 + t] = icur[t];
    }
}

// ---------------------------------------------------------------------------
// per (r, b, i): build LDS hash of the 1000 scattered candidates (coalesced
// e22n row), compute e222e row -> loss, then top-100 columns by value via
// in-LDS bitonic sort of the 2048 hash slots.
// ---------------------------------------------------------------------------
__global__ __launch_bounds__(256) void scatter_loss_topk_kernel(
    const int* __restrict__ e2n_ind,   // [B][E][10]
    const float* __restrict__ e2n_val, // [B][E][10]
    const int* __restrict__ edges,     // [R][N][WK]
    const float* __restrict__ wts,     // [R][N][WK]
    const float* __restrict__ e2e,     // [B][R][E][E]
    int* __restrict__ top_ind,         // [BE][R][100]
    float* __restrict__ loss_acc)
{
    __shared__ int   hkey[HASH_SZ];
    __shared__ float hval[HASH_SZ];
    __shared__ int   s_ind[E_SZ * KTOP];
    __shared__ float s_val[E_SZ * KTOP];
    __shared__ float red[256];

    const int blk = blockIdx.x;
    const int r = blk >> 9;        // blk / 512
    const int be = blk & 511;
    const int b = be >> 7, i = be & 127;
    const int tid = threadIdx.x;

    for (int idx = tid; idx < E_SZ * KTOP; idx += 256) {
        s_ind[idx] = e2n_ind[(size_t)b * E_SZ * KTOP + idx];
        s_val[idx] = e2n_val[(size_t)b * E_SZ * KTOP + idx];
    }
    for (int idx = tid; idx < HASH_SZ; idx += 256) { hkey[idx] = -1; hval[idx] = 0.f; }
    __syncthreads();

    // scatter-add 1000 candidates into the hash
    const size_t rbase = (size_t)r * N_NODES * WK;
    for (int c = tid; c < KTOP * WK; c += 256) {
        int k = c / WK, wk = c - k * WK;
        int node = s_ind[i * KTOP + k];
        float v0 = s_val[i * KTOP + k];
        size_t off = rbase + (size_t)node * WK + wk;
        int col = edges[off];
        float v = v0 * wts[off];
        unsigned h = ((unsigned)col * 2654435761u) >> 21;  // top 11 bits
        for (;;) {
            int old = atomicCAS(&hkey[h], -1, col);
            if (old == -1 || old == col) { atomicAdd(&hval[h], v); break; }
            h = (h + 1) & HASH_MASK;
        }
    }
    __syncthreads();

    // e222e row i of batch b (vs all j), accumulate squared error
    float sq = 0.f;
    if (tid < E_SZ) {
        const int j = tid;
        float acc = 0.f;
        #pragma unroll
        for (int k = 0; k < KTOP; ++k) {
            int col = s_ind[j * KTOP + k];
            float vv = s_val[j * KTOP + k];
            unsigned h = ((unsigned)col * 2654435761u) >> 21;
            float g = 0.f;
            for (;;) {
                int kk = hkey[h];
                if (kk == col) { g = hval[h]; break; }
                if (kk == -1) break;
                h = (h + 1) & HASH_MASK;
            }
            acc += vv * g;
        }
        float d = acc - e2e[(((size_t)b * R_HEADS + r) * E_SZ + i) * E_SZ + j];
        sq = d * d;
    }
    red[tid] = sq;
    __syncthreads();
    for (int off = 128; off; off >>= 1) {
        if (tid < off) red[tid] += red[tid + off];
        __syncthreads();
    }
    if (tid == 0) atomicAdd(loss_acc, red[0]);
    __syncthreads();

    // bitonic sort (descending by value) of the 2048 hash slots
    for (int idx = tid; idx < HASH_SZ; idx += 256)
        if (hkey[idx] == -1) hval[idx] = -FLT_MAX;
    __syncthreads();
    for (int ksz = 2; ksz <= HASH_SZ; ksz <<= 1) {
        for (int jj = ksz >> 1; jj > 0; jj >>= 1) {
            for (int idx = tid; idx < HASH_SZ; idx += 256) {
                int ixj = idx ^ jj;
                if (ixj > idx) {
                    float v1 = hval[idx], v2 = hval[ixj];
                    bool sw = ((idx & ksz) == 0) ? (v1 < v2) : (v1 > v2);
                    if (sw) {
                        hval[idx] = v2; hval[ixj] = v1;
                        int kk = hkey[idx]; hkey[idx] = hkey[ixj]; hkey[ixj] = kk;
                    }
                }
            }
            __syncthreads();
        }
    }
    if (tid < READ_K)
        top_ind[((size_t)be * R_HEADS + r) * READ_K + tid] = hkey[tid];
}

// ---------------------------------------------------------------------------
// attention read: per (r,b,e) gather 110 value rows to LDS (stride 65 to
// avoid the stride-64 bank conflict), score vs qh, softmax, weighted sum.
// ---------------------------------------------------------------------------
__global__ __launch_bounds__(128) void attn_kernel(
    const float* __restrict__ qh,      // [BE][768]
    const int* __restrict__ e2n_ind,   // [BE][10]
    const int* __restrict__ top_ind,   // [BE][R][100]
    const float* __restrict__ memv,    // [R][N][64]
    float* __restrict__ attd)          // [BE][768]
{
    __shared__ float vv[SLOTS * 65];
    __shared__ int slots[SLOTS];
    __shared__ float qv[64];
    __shared__ float sc[SLOTS];
    __shared__ float red[128];

    const int blk = blockIdx.x;
    const int r = blk >> 9, be = blk & 511;
    const int tid = threadIdx.x;

    if (tid < KTOP) slots[tid] = e2n_ind[(size_t)be * KTOP + tid];
    else if (tid < SLOTS) slots[tid] = top_ind[((size_t)be * R_HEADS + r) * READ_K + (tid - KTOP)];
    if (tid < 64) qv[tid] = qh[(size_t)be * H_DIM + r * 64 + tid];
    __syncthreads();

    const size_t rb = (size_t)r * N_NODES * 64;
    for (int idx = tid; idx < SLOTS * 64; idx += 128) {
        int s = idx >> 6, d = idx & 63;
        vv[s * 65 + d] = memv[rb + (size_t)slots[s] * 64 + d];
    }
    __syncthreads();

    if (tid < SLOTS) {
        float dot = 0.f;
        const float* vp = vv + tid * 65;
        #pragma unroll 8
        for (int d = 0; d < 64; ++d) dot += qv[d] * vp[d];
        sc[tid] = dot * 0.125f;   // / sqrt(64)
    }
    __syncthreads();

    red[tid] = (tid < SLOTS) ? sc[tid] : -FLT_MAX;
    __syncthreads();
    for (int off = 64; off; off >>= 1) {
        if (tid < off) red[tid] = fmaxf(red[tid], red[tid + off]);
        __syncthreads();
    }
    float m = red[0];
    __syncthreads();
    float e = (tid < SLOTS) ? expf(sc[tid] - m) : 0.f;
    red[tid] = e;
    __syncthreads();
    for (int off = 64; off; off >>= 1) {
        if (tid < off) red[tid] += red[tid + off];
        __syncthreads();
    }
    float sum = red[0];
    if (tid < SLOTS) sc[tid] = e / sum;
    __syncthreads();

    if (tid < 64) {
        float acc = 0.f;
        for (int s = 0; s < SLOTS; ++s) acc += sc[s] * vv[s * 65 + tid];
        attd[(size_t)be * H_DIM + r * 64 + tid] = acc;
    }
}

// ---------------------------------------------------------------------------
// layernorm over H=768 per row
// ---------------------------------------------------------------------------
__global__ __launch_bounds__(256) void ln_kernel(
    const float* __restrict__ h, const float* __restrict__ g,
    const float* __restrict__ bta, float* __restrict__ out)
{
    const int be = blockIdx.x, tid = threadIdx.x;
    __shared__ float red[256];
    const float x0 = h[(size_t)be * 768 + tid];
    const float x1 = h[(size_t)be * 768 + 256 + tid];
    const float x2 = h[(size_t)be * 768 + 512 + tid];
    red[tid] = x0 + x1 + x2;
    __syncthreads();
    for (int off = 128; off; off >>= 1) { if (tid < off) red[tid] += red[tid + off]; __syncthreads(); }
    const float mu = red[0] * (1.f / 768.f);
    __syncthreads();
    const float d0 = x0 - mu, d1 = x1 - mu, d2 = x2 - mu;
    red[tid] = d0 * d0 + d1 * d1 + d2 * d2;
    __syncthreads();
    for (int off = 128; off; off >>= 1) { if (tid < off) red[tid] += red[tid + off]; __syncthreads(); }
    const float rstd = rsqrtf(red[0] * (1.f / 768.f) + 1e-5f);
    out[(size_t)be * 768 + tid]       = d0 * rstd * g[tid]       + bta[tid];
    out[(size_t)be * 768 + 256 + tid] = d1 * rstd * g[tid + 256] + bta[tid + 256];
    out[(size_t)be * 768 + 512 + tid] = d2 * rstd * g[tid + 512] + bta[tid + 512];
}

// ---------------------------------------------------------------------------
extern "C" void kernel_launch(void* const* d_in, const int* in_sizes, int n_in,
                              void* d_out, int out_size, void* d_ws, size_t ws_size,
                              hipStream_t stream)
{
    const float* elem_hiddens = (const float*)d_in[0];
    const float* e2e          = (const float*)d_in[1];
    const float* Wq_idx       = (const float*)d_in[2];
    const float* bq_idx       = (const float*)d_in[3];
    const float* key0         = (const float*)d_in[4];
    const float* key1         = (const float*)d_in[5];
    const float* key2         = (const float*)d_in[6];
    const float* key3         = (const float*)d_in[7];
    // d_in[8] = memory_keys: UNUSED by the reference output
    const float* memv         = (const float*)d_in[9];
    const float* wir_w        = (const float*)d_in[10];
    const float* Wq_mha       = (const float*)d_in[11];
    const float* bq_mha       = (const float*)d_in[12];
    const float* W1           = (const float*)d_in[13];
    const float* b1           = (const float*)d_in[14];
    const float* W2           = (const float*)d_in[15];
    const float* b2           = (const float*)d_in[16];
    const float* ln_g         = (const float*)d_in[17];
    const float* ln_b         = (const float*)d_in[18];
    const int*   wir_e        = (const int*)d_in[19];
    float* out = (float*)d_out;

    char* ws = (char*)d_ws;
    float* loss    = (float*)ws;                         // 256 B reserved
    float* q_idx   = (float*)(ws + 256);                 // 512*256
    float* qh      = q_idx + (size_t)BE * 256;           // 512*768
    float* e2n_val = qh + (size_t)BE * H_DIM;            // 512*10
    int*   e2n_ind = (int*)(e2n_val + BE * KTOP);        // 512*10
    int*   top_ind = e2n_ind + BE * KTOP;                // 512*12*100
    float* attd    = (float*)(top_ind + (size_t)BE * R_HEADS * READ_K); // 512*768
    float* h1      = attd + (size_t)BE * H_DIM;          // 512*3072
    float* h2      = h1 + (size_t)BE * INTER;            // 512*768

    zero_loss_kernel<<<1, 64, 0, stream>>>(loss);

    // projections
    gemm_kernel<<<dim3(256 / 64, BE / 64), 256, 0, stream>>>(
        elem_hiddens, Wq_idx, bq_idx, q_idx, BE, 256, H_DIM, 0);
    gemm_kernel<<<dim3(H_DIM / 64, BE / 64), 256, 0, stream>>>(
        elem_hiddens, Wq_mha, bq_mha, qh, BE, H_DIM, H_DIM, 0);

    // hierarchical indexer
    indexer_kernel<<<BE, 64, 0, stream>>>(q_idx, key0, key1, key2, key3,
                                          e2n_val, e2n_ind);

    // per (r,b,i): hash scatter, write-loss, top-100
    scatter_loss_topk_kernel<<<R_HEADS * BE, 256, 0, stream>>>(
        e2n_ind, e2n_val, wir_e, wir_w, e2e, top_ind, loss);

    // attention read over 110 slots per (b,e,r)
    attn_kernel<<<R_HEADS * BE, 128, 0, stream>>>(qh, e2n_ind, top_ind, memv, attd);

    // MLP
    gemm_kernel<<<dim3(INTER / 64, BE / 64), 256, 0, stream>>>(
        attd, W1, b1, h1, BE, INTER, H_DIM, 1);
    gemm_kernel<<<dim3(H_DIM / 64, BE / 64), 256, 0, stream>>>(
        h1, W2, b2, h2, BE, H_DIM, INTER, 0);

    // layernorm -> out[0..393215], loss -> out[393216]
    ln_kernel<<<BE, 256, 0, stream>>>(h2, ln_g, ln_b, out);
    write_loss_kernel<<<1, 64, 0, stream>>>(loss, out + (size_t)BE * H_DIM);
}

// Round 2
// 1878.434 us; speedup vs baseline: 1.2266x; 1.2266x over previous
//
#include <hip/hip_runtime.h>
#include <hip/hip_bf16.h>
#include <cfloat>
#include <cmath>

// Problem constants
#define H_DIM 768
#define IDX_D 64
#define KTOP 10
#define R_HEADS 12
#define READ_K 100
#define MD 64
#define WK 100
#define INTER 3072
#define N_NODES 50000
#define B_SZ 4
#define E_SZ 128
#define BE 512            // B*E
#define SLOTS 110         // KTOP + READ_K
#define HASH_SZ 2048
#define HASH_MASK 2047

// ---------------------------------------------------------------------------
// small utility kernels
// ---------------------------------------------------------------------------
__global__ void zero_loss_kernel(float* p) {
    if (threadIdx.x == 0 && blockIdx.x == 0) *p = 0.f;
}
__global__ void write_loss_kernel(const float* p, float* out) {
    if (threadIdx.x == 0 && blockIdx.x == 0) out[0] = *p / 65536.f;  // / (B*E*E)
}

// ---------------------------------------------------------------------------
// generic f32 GEMM:  C[M,N] = A[M,K] @ B[K,N] + bias[N], optional exact GELU
// 64x64 tile, 256 threads, 4x4 micro-tile, K-tile 16. All dims divide evenly.
// ---------------------------------------------------------------------------
__global__ __launch_bounds__(256) void gemm_kernel(
    const float* __restrict__ A, const float* __restrict__ Bm,
    const float* __restrict__ bias, float* __restrict__ C,
    int M, int N, int K, int act)
{
    __shared__ float As[16][65];
    __shared__ float Bs[16][65];
    const int tid = threadIdx.x;
    const int tx = tid & 15, ty = tid >> 4;
    const int m0 = blockIdx.y * 64, n0 = blockIdx.x * 64;

    float acc[4][4] = {};
    for (int k0 = 0; k0 < K; k0 += 16) {
        for (int l = tid; l < 1024; l += 256) {
            int mm = l >> 4, kk = l & 15;
            As[kk][mm] = A[(size_t)(m0 + mm) * K + k0 + kk];
        }
        for (int l = tid; l < 1024; l += 256) {
            int kk = l >> 6, nn = l & 63;
            Bs[kk][nn] = Bm[(size_t)(k0 + kk) * N + n0 + nn];
        }
        __syncthreads();
        #pragma unroll
        for (int kk = 0; kk < 16; ++kk) {
            float av[4], bv[4];
            #pragma unroll
            for (int u = 0; u < 4; ++u) av[u] = As[kk][ty * 4 + u];
            #pragma unroll
            for (int v = 0; v < 4; ++v) bv[v] = Bs[kk][tx * 4 + v];
            #pragma unroll
            for (int u = 0; u < 4; ++u)
                #pragma unroll
                for (int v = 0; v < 4; ++v) acc[u][v] += av[u] * bv[v];
        }
        __syncthreads();
    }
    #pragma unroll
    for (int u = 0; u < 4; ++u) {
        int m = m0 + ty * 4 + u;
        #pragma unroll
        for (int v = 0; v < 4; ++v) {
            int n = n0 + tx * 4 + v;
            float x = acc[u][v] + bias[n];
            if (act) x = 0.5f * x * (1.f + erff(x * 0.70710678118654752f)); // exact gelu
            C[(size_t)m * N + n] = x;
        }
    }
}

// ---------------------------------------------------------------------------
// indexer: hierarchical product-key top-k.  1 block (64 threads = 1 wave) per
// (b,e) row.  Sets at each level are order-invariant downstream, so iterative
// argmax extraction is sufficient.
// ---------------------------------------------------------------------------
__device__ inline void wave_topk10(volatile float* a, int cnt,
                                   float* vnew, int* inew, int t)
{
    for (int iter = 0; iter < 10; ++iter) {
        float bv = -FLT_MAX;
        int bi = 0x7fffffff;
        for (int n = t; n < cnt; n += 64) {
            float v = a[n];
            if (v > bv) { bv = v; bi = n; }
        }
        #pragma unroll
        for (int off = 32; off; off >>= 1) {
            float ov = __shfl_xor(bv, off, 64);
            int   oi = __shfl_xor(bi, off, 64);
            if (ov > bv || (ov == bv && oi < bi)) { bv = ov; bi = oi; }
        }
        if (t == 0) { vnew[iter] = bv; inew[iter] = bi; a[bi] = -FLT_MAX; }
        __syncthreads();
    }
}

__global__ __launch_bounds__(64) void indexer_kernel(
    const float* __restrict__ qidx,   // [BE][256]
    const float* __restrict__ key0,   // [100][64]
    const float* __restrict__ key1,   // [100][10][64]
    const float* __restrict__ key2,   // [1000][10][64]
    const float* __restrict__ key3,   // [10000][5][64]
    float* __restrict__ e2n_val,      // [BE][10]
    int* __restrict__ e2n_ind)        // [BE][10]
{
    const int be = blockIdx.x;
    const int t = threadIdx.x;
    __shared__ float q[256];
    __shared__ float sraw[100];
    __shared__ float a[100];
    __shared__ float vnew[10]; __shared__ int inew[10];
    __shared__ float vcur[10]; __shared__ int icur[10];
    __shared__ float km[10], ks[10];

    for (int idx = t; idx < 256; idx += 64) q[idx] = qidx[(size_t)be * 256 + idx];
    __syncthreads();

    // ---- level 0: softmax over 100 nodes, top-10 ----
    for (int n = t; n < 100; n += 64) {
        float dot = 0.f;
        const float* kp = key0 + (size_t)n * 64;
        #pragma unroll 8
        for (int d = 0; d < 64; ++d) dot += q[d] * kp[d];
        sraw[n] = dot * 0.125f;   // / sqrt(64)
    }
    __syncthreads();
    float lm = -FLT_MAX;
    for (int n = t; n < 100; n += 64) lm = fmaxf(lm, sraw[n]);
    #pragma unroll
    for (int off = 32; off; off >>= 1) lm = fmaxf(lm, __shfl_xor(lm, off, 64));
    float lsum = 0.f;
    for (int n = t; n < 100; n += 64) { float e = expf(sraw[n] - lm); a[n] = e; lsum += e; }
    #pragma unroll
    for (int off = 32; off; off >>= 1) lsum += __shfl_xor(lsum, off, 64);
    __syncthreads();
    for (int n = t; n < 100; n += 64) a[n] /= lsum;
    __syncthreads();
    wave_topk10(a, 100, vnew, inew, t);
    if (t == 0) {
        float s = 0.f;
        for (int u = 0; u < 10; ++u) s += vnew[u];
        for (int u = 0; u < 10; ++u) { vcur[u] = vnew[u] / s; icur[u] = inew[u]; }
    }
    __syncthreads();

    // ---- levels 1..3 ----
    for (int lvl = 1; lvl < 4; ++lvl) {
        const int br = (lvl < 3) ? 10 : 5;
        const float* kb = (lvl == 1) ? key1 : ((lvl == 2) ? key2 : key3);
        const int cnt = 10 * br;
        const float* qv = q + lvl * 64;
        for (int c = t; c < cnt; c += 64) {
            int k = c / br, cc = c - k * br;
            const float* kp = kb + ((size_t)icur[k] * br + cc) * 64;
            float dot = 0.f;
            #pragma unroll 8
            for (int d = 0; d < 64; ++d) dot += qv[d] * kp[d];
            sraw[c] = dot * 0.125f;
        }
        __syncthreads();
        if (t < 10) {  // per-k softmax over branch
            float m = -FLT_MAX;
            for (int cc = 0; cc < br; ++cc) m = fmaxf(m, sraw[t * br + cc]);
            float s = 0.f;
            for (int cc = 0; cc < br; ++cc) s += expf(sraw[t * br + cc] - m);
            km[t] = m; ks[t] = s;
        }
        __syncthreads();
        for (int c = t; c < cnt; c += 64) {
            int k = c / br;
            a[c] = vcur[k] * expf(sraw[c] - km[k]) / ks[k];
        }
        __syncthreads();
        wave_topk10(a, cnt, vnew, inew, t);
        if (t == 0) {
            float s = 0.f;
            for (int u = 0; u < 10; ++u) s += vnew[u];
            int ni[10]; float nv[10];
            for (int u = 0; u < 10; ++u) {
                int f = inew[u];
                ni[u] = icur[f / br] * br + (f % br);
                nv[u] = vnew[u] / s;
            }
            for (int u = 0; u < 10; ++u) { icur[u] = ni[u]; vcur[u] = nv[u]; }
        }
        __syncthreads();
    }
    if (t < 10) {
        e2n_val[(size_t)be * 10 + t] = vcur[t];
        e2n_ind[(size_t)be * 10 + t] = icur[t];
    }
}

// ---------------------------------------------------------------------------
// per (r, b, i): build LDS hash of the 1000 scattered candidates (coalesced
// e22n row), compute e222e row -> loss, then top-100 columns by RADIX SELECT
// over float bits (positive floats are uint-monotonic; top-100 is guaranteed
// all-positive since each row has >=~500 positive nnz). Output is the SET of
// top-100 columns — order irrelevant (softmax over slots is perm-invariant).
// ---------------------------------------------------------------------------
__global__ __launch_bounds__(256) void scatter_loss_topk_kernel(
    const int* __restrict__ e2n_ind,   // [B][E][10]
    const float* __restrict__ e2n_val, // [B][E][10]
    const int* __restrict__ edges,     // [R][N][WK]
    const float* __restrict__ wts,     // [R][N][WK]
    const float* __restrict__ e2e,     // [B][R][E][E]
    int* __restrict__ top_ind,         // [BE][R][100]
    float* __restrict__ loss_acc)
{
    __shared__ int   hkey[HASH_SZ];
    __shared__ float hval[HASH_SZ];
    // pool phases: (1) s_ind[1280]+s_val[1280]  (2) hist[2048]  (3) bcol[1024]+bval[1024]
    __shared__ int   pool[2560];
    __shared__ float red[256];
    __shared__ int   chunkSuf[256];
    __shared__ int   s_t, s_above, s_cntA, s_cntB;

    const int blk = blockIdx.x;
    const int r = blk >> 9;        // blk / 512
    const int be = blk & 511;
    const int b = be >> 7, i = be & 127;
    const int tid = threadIdx.x;

    int* s_ind = pool;
    float* s_val = (float*)(pool + 1280);

    for (int idx = tid; idx < E_SZ * KTOP; idx += 256) {
        s_ind[idx] = e2n_ind[(size_t)b * E_SZ * KTOP + idx];
        s_val[idx] = e2n_val[(size_t)b * E_SZ * KTOP + idx];
    }
    for (int idx = tid; idx < HASH_SZ; idx += 256) { hkey[idx] = -1; hval[idx] = 0.f; }
    if (tid == 0) { s_t = -1; s_above = 0; s_cntA = 0; s_cntB = 0; }
    __syncthreads();

    // scatter-add 1000 candidates into the hash
    const size_t rbase = (size_t)r * N_NODES * WK;
    for (int c = tid; c < KTOP * WK; c += 256) {
        int k = c / WK, wk = c - k * WK;
        int node = s_ind[i * KTOP + k];
        float v0 = s_val[i * KTOP + k];
        size_t off = rbase + (size_t)node * WK + wk;
        int col = edges[off];
        float v = v0 * wts[off];
        unsigned h = ((unsigned)col * 2654435761u) >> 21;  // top 11 bits
        for (;;) {
            int old = atomicCAS(&hkey[h], -1, col);
            if (old == -1 || old == col) { atomicAdd(&hval[h], v); break; }
            h = (h + 1) & HASH_MASK;
        }
    }
    __syncthreads();

    // e222e row i of batch b (vs all j): 256 threads = 128 j x 2 k-halves
    {
        const int j = tid & 127, half = tid >> 7;
        float acc = 0.f;
        #pragma unroll
        for (int k = half * 5; k < half * 5 + 5; ++k) {
            int col = s_ind[j * KTOP + k];
            float vv = s_val[j * KTOP + k];
            unsigned h = ((unsigned)col * 2654435761u) >> 21;
            float g = 0.f;
            for (;;) {
                int kk = hkey[h];
                if (kk == col) { g = hval[h]; break; }
                if (kk == -1) break;
                h = (h + 1) & HASH_MASK;
            }
            acc += vv * g;
        }
        red[tid] = acc;
        __syncthreads();
        float sq = 0.f;
        if (tid < 128) {
            float tot = red[tid] + red[tid + 128];
            float d = tot - e2e[(((size_t)b * R_HEADS + r) * E_SZ + i) * E_SZ + tid];
            sq = d * d;
        }
        __syncthreads();
        red[tid] = sq;
        __syncthreads();
        for (int off = 128; off; off >>= 1) {
            if (tid < off) red[tid] += red[tid + off];
            __syncthreads();
        }
        if (tid == 0) atomicAdd(loss_acc, red[0]);
    }
    __syncthreads();   // also: s_ind/s_val dead from here -> pool reusable

    // ---- radix select: histogram on float bits [30:20] (2048 bins) ----
    int* hist = pool;
    for (int idx = tid; idx < HASH_SZ; idx += 256) hist[idx] = 0;
    __syncthreads();
    for (int idx = tid; idx < HASH_SZ; idx += 256) {
        float v = hval[idx];
        if (hkey[idx] != -1 && v > 0.f)
            atomicAdd(&hist[(__float_as_uint(v) >> 20) & 0x7FF], 1);
    }
    __syncthreads();
    {
        int csum = 0;
        #pragma unroll
        for (int bb = 0; bb < 8; ++bb) csum += hist[tid * 8 + bb];
        chunkSuf[tid] = csum;
    }
    __syncthreads();
    if (tid == 0) {   // suffix over 256 chunk sums (count in chunks ABOVE c)
        int suf = 0;
        for (int c = 255; c >= 0; --c) { int t0 = chunkSuf[c]; chunkSuf[c] = suf; suf += t0; }
    }
    __syncthreads();
    {   // find threshold bin t: count(bins > t) < 100 <= count(bins >= t)
        int cum = chunkSuf[tid];
        for (int bb = tid * 8 + 7; bb >= tid * 8; --bb) {
            int h = hist[bb];
            if (cum < READ_K && cum + h >= READ_K) { s_t = bb; s_above = cum; }
            cum += h;
        }
    }
    __syncthreads();
    const int tbin = s_t;   // -1 only if <100 positive values (guaranteed not; safe anyway)

    // ---- compaction pass: emit above-threshold cols, stash boundary bin ----
    int* bcol = pool;                 // reuses hist (dead after sync below)
    float* bval = (float*)(pool + 1024);
    __syncthreads();
    int* outp = top_ind + ((size_t)be * R_HEADS + r) * READ_K;
    for (int idx = tid; idx < HASH_SZ; idx += 256) {
        float v = hval[idx];
        if (hkey[idx] == -1 || v <= 0.f) continue;
        int bin = (__float_as_uint(v) >> 20) & 0x7FF;
        if (bin > tbin) {
            int p = atomicAdd(&s_cntA, 1);
            if (p < READ_K) outp[p] = hkey[idx];
        } else if (bin == tbin) {
            int p = atomicAdd(&s_cntB, 1);
            bcol[p] = hkey[idx]; bval[p] = v;
        }
    }
    __syncthreads();
    const int above = s_cntA;
    const int m = s_cntB;
    int rem = READ_K - above;
    if (rem >= m) {
        // take the whole boundary bin (rem==m when tbin valid); pad if short
        for (int idx = tid; idx < m; idx += 256) outp[above + idx] = bcol[idx];
        for (int idx = above + m + tid; idx < READ_K; idx += 256) outp[idx] = 0;
    } else if (tid < 64) {
        // wave-iterative argmax for the boundary remainder (m typically ~8-30)
        volatile float* bv_ = bval;
        for (int it = 0; it < rem; ++it) {
            float bvx = -FLT_MAX; int bi = -1;
            for (int n = tid; n < m; n += 64) {
                float v = bv_[n];
                if (v > bvx) { bvx = v; bi = n; }
            }
            #pragma unroll
            for (int off = 32; off; off >>= 1) {
                float ov = __shfl_xor(bvx, off, 64);
                int   oi = __shfl_xor(bi, off, 64);
                if (ov > bvx) { bvx = ov; bi = oi; }
            }
            if (tid == 0) { outp[above + it] = bcol[bi]; bv_[bi] = -FLT_MAX; }
        }
    }
}

// ---------------------------------------------------------------------------
// attention read: per (r,b,e) gather 110 value rows to LDS (stride 65 to
// avoid the stride-64 bank conflict), score vs qh, softmax, weighted sum.
// ---------------------------------------------------------------------------
__global__ __launch_bounds__(128) void attn_kernel(
    const float* __restrict__ qh,      // [BE][768]
    const int* __restrict__ e2n_ind,   // [BE][10]
    const int* __restrict__ top_ind,   // [BE][R][100]
    const float* __restrict__ memv,    // [R][N][64]
    float* __restrict__ attd)          // [BE][768]
{
    __shared__ float vv[SLOTS * 65];
    __shared__ int slots[SLOTS];
    __shared__ float qv[64];
    __shared__ float sc[SLOTS];
    __shared__ float red[128];

    const int blk = blockIdx.x;
    const int r = blk >> 9, be = blk & 511;
    const int tid = threadIdx.x;

    if (tid < KTOP) slots[tid] = e2n_ind[(size_t)be * KTOP + tid];
    else if (tid < SLOTS) slots[tid] = top_ind[((size_t)be * R_HEADS + r) * READ_K + (tid - KTOP)];
    if (tid < 64) qv[tid] = qh[(size_t)be * H_DIM + r * 64 + tid];
    __syncthreads();

    const size_t rb = (size_t)r * N_NODES * 64;
    for (int idx = tid; idx < SLOTS * 64; idx += 128) {
        int s = idx >> 6, d = idx & 63;
        vv[s * 65 + d] = memv[rb + (size_t)slots[s] * 64 + d];
    }
    __syncthreads();

    if (tid < SLOTS) {
        float dot = 0.f;
        const float* vp = vv + tid * 65;
        #pragma unroll 8
        for (int d = 0; d < 64; ++d) dot += qv[d] * vp[d];
        sc[tid] = dot * 0.125f;   // / sqrt(64)
    }
    __syncthreads();

    red[tid] = (tid < SLOTS) ? sc[tid] : -FLT_MAX;
    __syncthreads();
    for (int off = 64; off; off >>= 1) {
        if (tid < off) red[tid] = fmaxf(red[tid], red[tid + off]);
        __syncthreads();
    }
    float m = red[0];
    __syncthreads();
    float e = (tid < SLOTS) ? expf(sc[tid] - m) : 0.f;
    red[tid] = e;
    __syncthreads();
    for (int off = 64; off; off >>= 1) {
        if (tid < off) red[tid] += red[tid + off];
        __syncthreads();
    }
    float sum = red[0];
    if (tid < SLOTS) sc[tid] = e / sum;
    __syncthreads();

    if (tid < 64) {
        float acc = 0.f;
        for (int s = 0; s < SLOTS; ++s) acc += sc[s] * vv[s * 65 + tid];
        attd[(size_t)be * H_DIM + r * 64 + tid] = acc;
    }
}

// ---------------------------------------------------------------------------
// layernorm over H=768 per row
// ---------------------------------------------------------------------------
__global__ __launch_bounds__(256) void ln_kernel(
    const float* __restrict__ h, const float* __restrict__ g,
    const float* __restrict__ bta, float* __restrict__ out)
{
    const int be = blockIdx.x, tid = threadIdx.x;
    __shared__ float red[256];
    const float x0 = h[(size_t)be * 768 + tid];
    const float x1 = h[(size_t)be * 768 + 256 + tid];
    const float x2 = h[(size_t)be * 768 + 512 + tid];
    red[tid] = x0 + x1 + x2;
    __syncthreads();
    for (int off = 128; off; off >>= 1) { if (tid < off) red[tid] += red[tid + off]; __syncthreads(); }
    const float mu = red[0] * (1.f / 768.f);
    __syncthreads();
    const float d0 = x0 - mu, d1 = x1 - mu, d2 = x2 - mu;
    red[tid] = d0 * d0 + d1 * d1 + d2 * d2;
    __syncthreads();
    for (int off = 128; off; off >>= 1) { if (tid < off) red[tid] += red[tid + off]; __syncthreads(); }
    const float rstd = rsqrtf(red[0] * (1.f / 768.f) + 1e-5f);
    out[(size_t)be * 768 + tid]       = d0 * rstd * g[tid]       + bta[tid];
    out[(size_t)be * 768 + 256 + tid] = d1 * rstd * g[tid + 256] + bta[tid + 256];
    out[(size_t)be * 768 + 512 + tid] = d2 * rstd * g[tid + 512] + bta[tid + 512];
}

// ---------------------------------------------------------------------------
extern "C" void kernel_launch(void* const* d_in, const int* in_sizes, int n_in,
                              void* d_out, int out_size, void* d_ws, size_t ws_size,
                              hipStream_t stream)
{
    const float* elem_hiddens = (const float*)d_in[0];
    const float* e2e          = (const float*)d_in[1];
    const float* Wq_idx       = (const float*)d_in[2];
    const float* bq_idx       = (const float*)d_in[3];
    const float* key0         = (const float*)d_in[4];
    const float* key1         = (const float*)d_in[5];
    const float* key2         = (const float*)d_in[6];
    const float* key3         = (const float*)d_in[7];
    // d_in[8] = memory_keys: UNUSED by the reference output
    const float* memv         = (const float*)d_in[9];
    const float* wir_w        = (const float*)d_in[10];
    const float* Wq_mha       = (const float*)d_in[11];
    const float* bq_mha       = (const float*)d_in[12];
    const float* W1           = (const float*)d_in[13];
    const float* b1           = (const float*)d_in[14];
    const float* W2           = (const float*)d_in[15];
    const float* b2           = (const float*)d_in[16];
    const float* ln_g         = (const float*)d_in[17];
    const float* ln_b         = (const float*)d_in[18];
    const int*   wir_e        = (const int*)d_in[19];
    float* out = (float*)d_out;

    char* ws = (char*)d_ws;
    float* loss    = (float*)ws;                         // 256 B reserved
    float* q_idx   = (float*)(ws + 256);                 // 512*256
    float* qh      = q_idx + (size_t)BE * 256;           // 512*768
    float* e2n_val = qh + (size_t)BE * H_DIM;            // 512*10
    int*   e2n_ind = (int*)(e2n_val + BE * KTOP);        // 512*10
    int*   top_ind = e2n_ind + BE * KTOP;                // 512*12*100
    float* attd    = (float*)(top_ind + (size_t)BE * R_HEADS * READ_K); // 512*768
    float* h1      = attd + (size_t)BE * H_DIM;          // 512*3072
    float* h2      = h1 + (size_t)BE * INTER;            // 512*768

    zero_loss_kernel<<<1, 64, 0, stream>>>(loss);

    // projections
    gemm_kernel<<<dim3(256 / 64, BE / 64), 256, 0, stream>>>(
        elem_hiddens, Wq_idx, bq_idx, q_idx, BE, 256, H_DIM, 0);
    gemm_kernel<<<dim3(H_DIM / 64, BE / 64), 256, 0, stream>>>(
        elem_hiddens, Wq_mha, bq_mha, qh, BE, H_DIM, H_DIM, 0);

    // hierarchical indexer
    indexer_kernel<<<BE, 64, 0, stream>>>(q_idx, key0, key1, key2, key3,
                                          e2n_val, e2n_ind);

    // per (r,b,i): hash scatter, write-loss, top-100 via radix select
    scatter_loss_topk_kernel<<<R_HEADS * BE, 256, 0, stream>>>(
        e2n_ind, e2n_val, wir_e, wir_w, e2e, top_ind, loss);

    // attention read over 110 slots per (b,e,r)
    attn_kernel<<<R_HEADS * BE, 128, 0, stream>>>(qh, e2n_ind, top_ind, memv, attd);

    // MLP
    gemm_kernel<<<dim3(INTER / 64, BE / 64), 256, 0, stream>>>(
        attd, W1, b1, h1, BE, INTER, H_DIM, 1);
    gemm_kernel<<<dim3(H_DIM / 64, BE / 64), 256, 0, stream>>>(
        h1, W2, b2, h2, BE, H_DIM, INTER, 0);

    // layernorm -> out[0..393215], loss -> out[393216]
    ln_kernel<<<BE, 256, 0, stream>>>(h2, ln_g, ln_b, out);
    write_loss_kernel<<<1, 64, 0, stream>>>(loss, out + (size_t)BE * H_DIM);
}